// Round 3
// baseline (317.596 us; speedup 1.0000x reference)
//
#include <hip/hip_runtime.h>
#include <hip/hip_cooperative_groups.h>
#include <stdint.h>

namespace cg = cooperative_groups;

#define GSZ 256
#define NV (GSZ*GSZ)
#define NS 2048
#define CELLS (255*255)          // 65025 cells per mesh
#define FH CELLS
#define NF (2*CELLS)             // 130050 faces per mesh
#define NBLK 512
#define NTHR 256
#define NTOT (NBLK*NTHR)

struct F3 { float x, y, z; };

__device__ __forceinline__ F3 ldv3(const float* __restrict__ p, int idx) {
    const float* q = p + 3*(size_t)idx;
    F3 r; r.x = q[0]; r.y = q[1]; r.z = q[2]; return r;
}
__device__ __forceinline__ F3 f3sub(F3 a, F3 b) { return F3{a.x-b.x, a.y-b.y, a.z-b.z}; }
__device__ __forceinline__ F3 f3cross(F3 a, F3 b) {
    return F3{a.y*b.z - a.z*b.y, a.z*b.x - a.x*b.z, a.x*b.y - a.y*b.x};
}
__device__ __forceinline__ float f3dot(F3 a, F3 b) { return a.x*b.x + a.y*b.y + a.z*b.z; }

__device__ __forceinline__ uint64_t splitmix64(uint64_t& s) {
    s += 0x9E3779B97F4A7C15ULL;
    uint64_t z = s;
    z = (z ^ (z >> 30)) * 0xBF58476D1CE4E5B9ULL;
    z = (z ^ (z >> 27)) * 0x94D049BB133111EBULL;
    return z ^ (z >> 31);
}

__shared__ float4 g_tile[2048];      // 32 KB — chamfer dst points
__shared__ float  g_sred[4];
__shared__ float  g_mred[256];
__shared__ float  g_sMaxA;
__shared__ double g_dred[5][4];

// result on thread 0 only
__device__ __forceinline__ float blockReduceSum256(float v) {
    __syncthreads();                 // protect g_sred reuse across calls
    int lane = threadIdx.x & 63, w = threadIdx.x >> 6;
    #pragma unroll
    for (int o = 32; o > 0; o >>= 1) v += __shfl_down(v, o, 64);
    if (lane == 0) g_sred[w] = v;
    __syncthreads();
    if (threadIdx.x == 0) v = g_sred[0] + g_sred[1] + g_sred[2] + g_sred[3];
    return v;
}

__global__ void __launch_bounds__(256, 2)
k_all(const float* __restrict__ vp, const float* __restrict__ vt,
      const int* __restrict__ edges, const int* __restrict__ ncp,
      int B, int E, int P,
      float* __restrict__ areas, float* __restrict__ samples,
      float* __restrict__ blockmax, float* __restrict__ chamPart,
      float* __restrict__ partE, float* __restrict__ partP,
      float* __restrict__ partL, float* __restrict__ out) {
    cg::grid_group grid = cg::this_grid();
    const int tid = threadIdx.x, bid = blockIdx.x;
    const int gid = bid*NTHR + tid;

    // ---------------- Phase A: areas + blockmax, mesh losses --------------
    float mloc = 0.f;
    {
        int total = 2*B*CELLS;
        for (int c = gid; c < total; c += NTOT) {
            int m = c / CELLS, cc = c - m*CELLS;
            int i = cc / 255, j = cc - i*255;
            const float* verts = (m < B ? vp + (size_t)m*NV*3
                                        : vt + (size_t)(m-B)*NV*3);
            int v = i*GSZ + j;
            F3 v00 = ldv3(verts, v),       v01 = ldv3(verts, v+1);
            F3 v10 = ldv3(verts, v+GSZ),   v11 = ldv3(verts, v+GSZ+1);
            F3 c1 = f3cross(f3sub(v01, v00), f3sub(v10, v00));
            F3 c2 = f3cross(f3sub(v11, v01), f3sub(v10, v01));
            float a1 = 0.5f * sqrtf(f3dot(c1, c1));
            float a2 = 0.5f * sqrtf(f3dot(c2, c2));
            size_t base = (size_t)m*NF;
            areas[base + cc]      = a1;
            areas[base + FH + cc] = a2;
            mloc = fmaxf(mloc, fmaxf(a1, a2));
        }
    }
    {   // block max -> blockmax[bid]
        #pragma unroll
        for (int o = 32; o > 0; o >>= 1) mloc = fmaxf(mloc, __shfl_down(mloc, o, 64));
        int lane = tid & 63, w = tid >> 6;
        if (lane == 0) g_sred[w] = mloc;
        __syncthreads();
        if (tid == 0)
            blockmax[bid] = fmaxf(fmaxf(g_sred[0], g_sred[1]),
                                  fmaxf(g_sred[2], g_sred[3]));
    }
    float accE = 0.f, accP = 0.f, accL = 0.f;
    {   // edge loss
        int total = B*E;
        for (int g = gid; g < total; g += NTOT) {
            int b = g / E, e = g - b*E;
            const float* verts = vp + (size_t)b*NV*3;
            int2 ed = ((const int2*)edges)[e];
            F3 d = f3sub(ldv3(verts, ed.x), ldv3(verts, ed.y));
            accE += f3dot(d, d);
        }
    }
    {   // normal consistency
        int total = B*P;
        for (int g = gid; g < total; g += NTOT) {
            int b = g / P, p = g - b*P;
            const float* verts = vp + (size_t)b*NV*3;
            int4 q = ((const int4*)ncp)[p];
            F3 v0 = ldv3(verts, q.x), v1 = ldv3(verts, q.y);
            F3 a = ldv3(verts, q.z), bb = ldv3(verts, q.w);
            F3 e = f3sub(v1, v0);
            F3 n0 = f3cross(e, f3sub(a, v0));
            F3 n1 = f3cross(f3sub(bb, v0), e);     // == -cross(e, bb-v0)
            float num = f3dot(n0, n1);
            float den = fmaxf(sqrtf(f3dot(n0, n0)), 1e-8f) *
                        fmaxf(sqrtf(f3dot(n1, n1)), 1e-8f);
            accP += 1.f - num / den;
        }
    }
    {   // uniform laplacian (analytic grid stencil)
        int total = B*NV;
        for (int g = gid; g < total; g += NTOT) {
            int b = g >> 16, idx = g & (NV-1);
            int i = idx >> 8, j = idx & 255;
            const float* verts = vp + (size_t)b*NV*3;
            F3 ctr = ldv3(verts, idx);
            float nx = 0.f, ny = 0.f, nz = 0.f; int deg = 0;
            #define ADDN(ii, jj) { F3 n_ = ldv3(verts, (ii)*GSZ + (jj)); \
                                   nx += n_.x; ny += n_.y; nz += n_.z; ++deg; }
            if (j > 0)               ADDN(i, j-1);
            if (j < GSZ-1)           ADDN(i, j+1);
            if (i > 0)               ADDN(i-1, j);
            if (i < GSZ-1)           ADDN(i+1, j);
            if (i < GSZ-1 && j > 0)  ADDN(i+1, j-1);
            if (i > 0 && j < GSZ-1)  ADDN(i-1, j+1);
            #undef ADDN
            float inv = 1.f / (float)deg;
            float lx = nx*inv - ctr.x, ly = ny*inv - ctr.y, lz = nz*inv - ctr.z;
            accL += sqrtf(lx*lx + ly*ly + lz*lz);
        }
    }
    {
        float s = blockReduceSum256(accE);
        if (tid == 0) partE[bid] = s;
        s = blockReduceSum256(accP);
        if (tid == 0) partP[bid] = s;
        s = blockReduceSum256(accL);
        if (tid == 0) partL[bid] = s;
    }

    grid.sync();

    // ---------------- Phase B: global max area + sampling -----------------
    {
        float m = 0.f;
        for (int k = tid; k < NBLK; k += NTHR) m = fmaxf(m, blockmax[k]);
        #pragma unroll
        for (int o = 32; o > 0; o >>= 1) m = fmaxf(m, __shfl_down(m, o, 64));
        int lane = tid & 63, w = tid >> 6;
        __syncthreads();
        if (lane == 0) g_sred[w] = m;
        __syncthreads();
        if (tid == 0) g_sMaxA = fmaxf(fmaxf(g_sred[0], g_sred[1]),
                                      fmaxf(g_sred[2], g_sred[3]));
        __syncthreads();
    }
    if (gid < 2*B*NS) {
        float maxA = g_sMaxA;
        int cloud = gid / (B*NS);
        int rem = gid - cloud*(B*NS);
        int b = rem / NS;
        const float* verts = (cloud ? vt : vp) + (size_t)b*NV*3;
        const float* am = areas + (size_t)(cloud*B + b)*NF;

        uint64_t st = ((uint64_t)(gid + 1) * 0x9E3779B97F4A7C15ULL) ^ 0xC0FFEE123456789ULL;
        int f = 0;
        for (int round = 0; round < 64; ++round) {
            uint64_t r0 = splitmix64(st), r1 = splitmix64(st);
            uint64_t r2 = splitmix64(st), r3 = splitmix64(st);
            int f0 = (int)(((uint64_t)(uint32_t)r0 * (uint32_t)NF) >> 32);
            int f1 = (int)(((uint64_t)(uint32_t)r1 * (uint32_t)NF) >> 32);
            int f2 = (int)(((uint64_t)(uint32_t)r2 * (uint32_t)NF) >> 32);
            int f3 = (int)(((uint64_t)(uint32_t)r3 * (uint32_t)NF) >> 32);
            float a0 = am[f0], a1 = am[f1], a2 = am[f2], a3 = am[f3];
            float u0 = ((uint32_t)(r0 >> 40)) * (1.f/16777216.f);
            float u1 = ((uint32_t)(r1 >> 40)) * (1.f/16777216.f);
            float u2 = ((uint32_t)(r2 >> 40)) * (1.f/16777216.f);
            float u3 = ((uint32_t)(r3 >> 40)) * (1.f/16777216.f);
            if (u0 * maxA <= a0) { f = f0; break; }
            if (u1 * maxA <= a1) { f = f1; break; }
            if (u2 * maxA <= a2) { f = f2; break; }
            if (u3 * maxA <= a3) { f = f3; break; }
            f = f3;
        }
        int i0, i1, i2;
        if (f < FH) {
            int c = f;  int i = c / 255, j = c - i*255;  int v = i*GSZ + j;
            i0 = v; i1 = v + 1; i2 = v + GSZ;
        } else {
            int c = f - FH;  int i = c / 255, j = c - i*255;  int v = i*GSZ + j;
            i0 = v + 1; i1 = v + GSZ + 1; i2 = v + GSZ;
        }
        F3 v0 = ldv3(verts, i0), v1 = ldv3(verts, i1), v2 = ldv3(verts, i2);
        uint64_t r = splitmix64(st);
        float u0 = ((uint32_t)r >> 8) * (1.f/16777216.f);
        float u1 = ((uint32_t)(r >> 32) >> 8) * (1.f/16777216.f);
        float su = sqrtf(u0);
        float w0 = 1.f - su, w1 = su * (1.f - u1), w2 = su * u1;
        float* o = samples + (size_t)gid*3;
        o[0] = w0*v0.x + w1*v1.x + w2*v2.x;
        o[1] = w0*v0.y + w1*v1.y + w2*v2.y;
        o[2] = w0*v0.z + w1*v1.z + w2*v2.z;
    }

    grid.sync();

    // ---------------- Phase C: chamfer ------------------------------------
    // 512 blocks = 2 dirs x B x 32 chunks of 64 src points.
    if (bid < 2*B*32) {
        int dir = bid / (B*32);
        int rem = bid - dir*(B*32);
        int b = rem >> 5, chunk = rem & 31;
        const float* src = samples + ((size_t)dir*B + b)*NS*3;
        const float* dst = samples + ((size_t)(1-dir)*B + b)*NS*3;
        for (int k = tid; k < 2048; k += NTHR) {
            const float* p = dst + (size_t)k*3;
            g_tile[k] = make_float4(p[0], p[1], p[2], 0.f);
        }
        int sl = tid & 63;                 // src lane in chunk
        int q  = tid >> 6;                 // dst quarter 0..3
        const float* sp = src + (size_t)(chunk*64 + sl)*3;
        float px = sp[0], py = sp[1], pz = sp[2];
        __syncthreads();
        float mn = 3.402823466e38f;
        int j0 = q*512;
        #pragma unroll 4
        for (int j = j0; j < j0 + 512; ++j) {
            float4 t = g_tile[j];
            float dx = px-t.x, dy = py-t.y, dz = pz-t.z;
            mn = fminf(mn, fmaf(dx, dx, fmaf(dy, dy, dz*dz)));
        }
        g_mred[tid] = mn;
        __syncthreads();
        if (tid < 64) {
            float m = fminf(fminf(g_mred[tid], g_mred[tid+64]),
                            fminf(g_mred[tid+128], g_mred[tid+192]));
            #pragma unroll
            for (int o = 32; o > 0; o >>= 1) m += __shfl_down(m, o, 64);
            if (tid == 0) chamPart[bid] = m;
        }
    }

    grid.sync();

    // ---------------- Phase D: final fp64 reduction -----------------------
    if (bid == 0) {
        int nPerDir = B*32;
        double a0 = 0, a1 = 0, aE = 0, aP = 0, aL = 0;
        for (int k = tid; k < 2*nPerDir; k += NTHR) {
            double v = (double)chamPart[k];
            if (k < nPerDir) a0 += v; else a1 += v;
        }
        for (int k = tid; k < NBLK; k += NTHR) {
            aE += (double)partE[k];
            aP += (double)partP[k];
            aL += (double)partL[k];
        }
        double v5[5] = {a0, a1, aE, aP, aL};
        int lane = tid & 63, w = tid >> 6;
        #pragma unroll
        for (int r = 0; r < 5; ++r) {
            double x = v5[r];
            #pragma unroll
            for (int o = 32; o > 0; o >>= 1) x += __shfl_down(x, o, 64);
            if (lane == 0) g_dred[r][w] = x;
        }
        __syncthreads();
        if (tid == 0) {
            double bn = (double)B * NS;
            double ch = (g_dred[0][0]+g_dred[0][1]+g_dred[0][2]+g_dred[0][3]) / bn
                      + (g_dred[1][0]+g_dred[1][1]+g_dred[1][2]+g_dred[1][3]) / bn;
            double ed = (g_dred[2][0]+g_dred[2][1]+g_dred[2][2]+g_dred[2][3]) / ((double)B*E);
            double no = (g_dred[3][0]+g_dred[3][1]+g_dred[3][2]+g_dred[3][3]) / ((double)B*P);
            double la = (g_dred[4][0]+g_dred[4][1]+g_dred[4][2]+g_dred[4][3]) / ((double)B*NV);
            double loss = ch + ed + 0.1*no + 0.1*la;
            out[0] = (float)loss; out[1] = (float)ch; out[2] = (float)ed;
            out[3] = (float)no;   out[4] = (float)la;
        }
    }
}

extern "C" void kernel_launch(void* const* d_in, const int* in_sizes, int n_in,
                              void* d_out, int out_size, void* d_ws, size_t ws_size,
                              hipStream_t stream) {
    const float* vp = (const float*)d_in[0];
    const float* vt = (const float*)d_in[1];
    const int* edges = (const int*)d_in[3];
    const int* ncp   = (const int*)d_in[4];
    int B = in_sizes[0] / (3*NV);
    int E = in_sizes[3] / 2;
    int P = in_sizes[4] / 4;

    char* ws = (char*)d_ws;
    size_t off = 0;
    float* areas    = (float*)(ws + off); off += (size_t)2*B*NF*sizeof(float);   // 8.3 MB
    float* samples  = (float*)(ws + off); off += (size_t)2*B*NS*3*sizeof(float); // 393 KB
    float* blockmax = (float*)(ws + off); off += NBLK*sizeof(float);
    float* chamPart = (float*)(ws + off); off += NBLK*sizeof(float);
    float* partE    = (float*)(ws + off); off += NBLK*sizeof(float);
    float* partP    = (float*)(ws + off); off += NBLK*sizeof(float);
    float* partL    = (float*)(ws + off); off += NBLK*sizeof(float);
    float* out      = (float*)d_out;

    void* args[] = { &vp, &vt, &edges, &ncp, &B, &E, &P,
                     &areas, &samples, &blockmax, &chamPart,
                     &partE, &partP, &partL, &out };
    hipLaunchCooperativeKernel((void*)k_all, dim3(NBLK), dim3(NTHR),
                               args, 0, stream);
}

// Round 4
// 165.593 us; speedup vs baseline: 1.9179x; 1.9179x over previous
//
#include <hip/hip_runtime.h>
#include <stdint.h>

#define GSZ 256
#define NV (GSZ*GSZ)
#define NS 2048
#define CELLS (255*255)          // 65025 cells per mesh
#define FH CELLS
#define NF (2*CELLS)             // 130050 faces per mesh

struct F3 { float x, y, z; };

__device__ __forceinline__ F3 ldv3(const float* __restrict__ p, int idx) {
    const float* q = p + 3*(size_t)idx;
    F3 r; r.x = q[0]; r.y = q[1]; r.z = q[2]; return r;
}
__device__ __forceinline__ F3 f3sub(F3 a, F3 b) { return F3{a.x-b.x, a.y-b.y, a.z-b.z}; }
__device__ __forceinline__ F3 f3cross(F3 a, F3 b) {
    return F3{a.y*b.z - a.z*b.y, a.z*b.x - a.x*b.z, a.x*b.y - a.y*b.x};
}
__device__ __forceinline__ float f3dot(F3 a, F3 b) { return a.x*b.x + a.y*b.y + a.z*b.z; }

__device__ __forceinline__ uint64_t splitmix64(uint64_t& s) {
    s += 0x9E3779B97F4A7C15ULL;
    uint64_t z = s;
    z = (z ^ (z >> 30)) * 0xBF58476D1CE4E5B9ULL;
    z = (z ^ (z >> 27)) * 0x94D049BB133111EBULL;
    return z ^ (z >> 31);
}

// ---------------------------------------------------------------------------
// k_prep: segmented block ranges — [0,nbA): areas+blockmax; [nbA,nbA+nbE):
// edge partials (4 elems/thread); then normal partials; then laplacian.
// Large grid (≈7.6k blocks) → full occupancy for latency-bound gathers.
__global__ void __launch_bounds__(256)
k_prep(const float* __restrict__ vp, const float* __restrict__ vt,
       const int* __restrict__ edges, const int* __restrict__ ncp,
       int B, int E, int P, int nbA, int nbE, int nbP,
       float* __restrict__ areas, float* __restrict__ blockmax,
       float* __restrict__ partE, float* __restrict__ partP,
       float* __restrict__ partL, unsigned int* __restrict__ counter) {
    __shared__ float sred[4];
    const int tid = threadIdx.x, bx = blockIdx.x;
    const int lane = tid & 63, w = tid >> 6;
    if (bx == 0 && tid == 0) *counter = 0u;

    if (bx < nbA) {
        // ---- face areas + block max ----
        float mloc = 0.f;
        int gid = bx*256 + tid;
        if (gid < 2*B*CELLS) {
            int m = gid / CELLS, cc = gid - m*CELLS;
            int i = cc / 255, j = cc - i*255;
            const float* verts = (m < B ? vp + (size_t)m*NV*3
                                        : vt + (size_t)(m-B)*NV*3);
            int v = i*GSZ + j;
            F3 v00 = ldv3(verts, v),     v01 = ldv3(verts, v+1);
            F3 v10 = ldv3(verts, v+GSZ), v11 = ldv3(verts, v+GSZ+1);
            F3 c1 = f3cross(f3sub(v01, v00), f3sub(v10, v00));
            F3 c2 = f3cross(f3sub(v11, v01), f3sub(v10, v01));
            float a1 = 0.5f * sqrtf(f3dot(c1, c1));
            float a2 = 0.5f * sqrtf(f3dot(c2, c2));
            size_t base = (size_t)m*NF;
            areas[base + cc]      = a1;
            areas[base + FH + cc] = a2;
            mloc = fmaxf(a1, a2);
        }
        #pragma unroll
        for (int o = 32; o > 0; o >>= 1) mloc = fmaxf(mloc, __shfl_down(mloc, o, 64));
        if (lane == 0) sred[w] = mloc;
        __syncthreads();
        if (tid == 0)
            blockmax[bx] = fmaxf(fmaxf(sred[0], sred[1]), fmaxf(sred[2], sred[3]));
        return;
    }

    float acc = 0.f;
    float* dst; int slot;
    if (bx < nbA + nbE) {
        // ---- edge loss ----
        int base = (bx - nbA)*1024;
        #pragma unroll
        for (int c = 0; c < 4; ++c) {
            int g = base + c*256 + tid;
            if (g < B*E) {
                int b = g / E, e = g - b*E;
                const float* verts = vp + (size_t)b*NV*3;
                int2 ed = ((const int2*)edges)[e];
                F3 d = f3sub(ldv3(verts, ed.x), ldv3(verts, ed.y));
                acc += f3dot(d, d);
            }
        }
        dst = partE; slot = bx - nbA;
    } else if (bx < nbA + nbE + nbP) {
        // ---- normal consistency ----
        int base = (bx - nbA - nbE)*1024;
        #pragma unroll
        for (int c = 0; c < 4; ++c) {
            int g = base + c*256 + tid;
            if (g < B*P) {
                int b = g / P, p = g - b*P;
                const float* verts = vp + (size_t)b*NV*3;
                int4 q = ((const int4*)ncp)[p];
                F3 v0 = ldv3(verts, q.x), v1 = ldv3(verts, q.y);
                F3 a = ldv3(verts, q.z), bb = ldv3(verts, q.w);
                F3 e = f3sub(v1, v0);
                F3 n0 = f3cross(e, f3sub(a, v0));
                F3 n1 = f3cross(f3sub(bb, v0), e);   // == -cross(e, bb-v0)
                float num = f3dot(n0, n1);
                float den = fmaxf(sqrtf(f3dot(n0, n0)), 1e-8f) *
                            fmaxf(sqrtf(f3dot(n1, n1)), 1e-8f);
                acc += 1.f - num / den;
            }
        }
        dst = partP; slot = bx - nbA - nbE;
    } else {
        // ---- uniform laplacian (analytic grid stencil) ----
        int base = (bx - nbA - nbE - nbP)*1024;
        #pragma unroll
        for (int c = 0; c < 4; ++c) {
            int g = base + c*256 + tid;        // < B*NV (exact multiple)
            int b = g >> 16, idx = g & (NV-1);
            int i = idx >> 8, j = idx & 255;
            const float* verts = vp + (size_t)b*NV*3;
            F3 ctr = ldv3(verts, idx);
            float nx = 0.f, ny = 0.f, nz = 0.f; int deg = 0;
            #define ADDN(ii, jj) { F3 n_ = ldv3(verts, (ii)*GSZ + (jj)); \
                                   nx += n_.x; ny += n_.y; nz += n_.z; ++deg; }
            if (j > 0)               ADDN(i, j-1);
            if (j < GSZ-1)           ADDN(i, j+1);
            if (i > 0)               ADDN(i-1, j);
            if (i < GSZ-1)           ADDN(i+1, j);
            if (i < GSZ-1 && j > 0)  ADDN(i+1, j-1);
            if (i > 0 && j < GSZ-1)  ADDN(i-1, j+1);
            #undef ADDN
            float inv = 1.f / (float)deg;
            float lx = nx*inv - ctr.x, ly = ny*inv - ctr.y, lz = nz*inv - ctr.z;
            acc += sqrtf(lx*lx + ly*ly + lz*lz);
        }
        dst = partL; slot = bx - nbA - nbE - nbP;
    }
    #pragma unroll
    for (int o = 32; o > 0; o >>= 1) acc += __shfl_down(acc, o, 64);
    if (lane == 0) sred[w] = acc;
    __syncthreads();
    if (tid == 0) dst[slot] = sred[0] + sred[1] + sred[2] + sred[3];
}

// ---------------------------------------------------------------------------
// k_sample: identical math/RNG to R2/R3 (verified absmax 0.0).
__global__ void __launch_bounds__(256)
k_sample(const float* __restrict__ vp, const float* __restrict__ vt,
         int B, const float* __restrict__ areas,
         const float* __restrict__ blockmax, int nbm,
         float* __restrict__ samples) {
    __shared__ float sred[4];
    __shared__ float sMaxA;
    float m = 0.f;
    for (int k = threadIdx.x; k < nbm; k += 256) m = fmaxf(m, blockmax[k]);
    #pragma unroll
    for (int o = 32; o > 0; o >>= 1) m = fmaxf(m, __shfl_down(m, o, 64));
    int lane = threadIdx.x & 63, w = threadIdx.x >> 6;
    if (lane == 0) sred[w] = m;
    __syncthreads();
    if (threadIdx.x == 0)
        sMaxA = fmaxf(fmaxf(sred[0], sred[1]), fmaxf(sred[2], sred[3]));
    __syncthreads();
    float maxA = sMaxA;

    int gid = blockIdx.x*256 + threadIdx.x;       // 2*B*NS threads exact
    int cloud = gid / (B*NS);
    int rem = gid - cloud*(B*NS);
    int b = rem / NS;
    const float* verts = (cloud ? vt : vp) + (size_t)b*NV*3;
    const float* am = areas + (size_t)(cloud*B + b)*NF;

    uint64_t st = ((uint64_t)(gid + 1) * 0x9E3779B97F4A7C15ULL) ^ 0xC0FFEE123456789ULL;
    int f = 0;
    for (int round = 0; round < 64; ++round) {
        uint64_t r0 = splitmix64(st), r1 = splitmix64(st);
        uint64_t r2 = splitmix64(st), r3 = splitmix64(st);
        int f0 = (int)(((uint64_t)(uint32_t)r0 * (uint32_t)NF) >> 32);
        int f1 = (int)(((uint64_t)(uint32_t)r1 * (uint32_t)NF) >> 32);
        int f2 = (int)(((uint64_t)(uint32_t)r2 * (uint32_t)NF) >> 32);
        int f3 = (int)(((uint64_t)(uint32_t)r3 * (uint32_t)NF) >> 32);
        float a0 = am[f0], a1 = am[f1], a2 = am[f2], a3 = am[f3];
        float u0 = ((uint32_t)(r0 >> 40)) * (1.f/16777216.f);
        float u1 = ((uint32_t)(r1 >> 40)) * (1.f/16777216.f);
        float u2 = ((uint32_t)(r2 >> 40)) * (1.f/16777216.f);
        float u3 = ((uint32_t)(r3 >> 40)) * (1.f/16777216.f);
        if (u0 * maxA <= a0) { f = f0; break; }
        if (u1 * maxA <= a1) { f = f1; break; }
        if (u2 * maxA <= a2) { f = f2; break; }
        if (u3 * maxA <= a3) { f = f3; break; }
        f = f3;
    }
    int i0, i1, i2;
    if (f < FH) {
        int c = f;  int i = c / 255, j = c - i*255;  int v = i*GSZ + j;
        i0 = v; i1 = v + 1; i2 = v + GSZ;
    } else {
        int c = f - FH;  int i = c / 255, j = c - i*255;  int v = i*GSZ + j;
        i0 = v + 1; i1 = v + GSZ + 1; i2 = v + GSZ;
    }
    F3 v0 = ldv3(verts, i0), v1 = ldv3(verts, i1), v2 = ldv3(verts, i2);
    uint64_t r = splitmix64(st);
    float u0 = ((uint32_t)r >> 8) * (1.f/16777216.f);
    float u1 = ((uint32_t)(r >> 32) >> 8) * (1.f/16777216.f);
    float su = sqrtf(u0);
    float w0 = 1.f - su, w1 = su * (1.f - u1), w2 = su * u1;
    float* o = samples + (size_t)gid*3;
    o[0] = w0*v0.x + w1*v1.x + w2*v2.x;
    o[1] = w0*v0.y + w1*v1.y + w2*v2.y;
    o[2] = w0*v0.z + w1*v1.z + w2*v2.z;
}

// ---------------------------------------------------------------------------
// k_chamfer: grid (64 chunk, B, 2 dir) = 1024 blocks. Block = 32 src pts;
// full 2048-pt dst tile in LDS (32 KB -> 4 blocks/CU). Thread = src(32) x
// octant(8): 256 distances each. Last block (atomic counter) does the final
// fp64 reduction of ALL partials and writes the 5 outputs.
__global__ void __launch_bounds__(256)
k_chamfer(const float* __restrict__ samples, int B,
          const float* __restrict__ partE, const float* __restrict__ partP,
          const float* __restrict__ partL, int nbE, int nbP, int nbL,
          int E, int P,
          float* __restrict__ chamPart, unsigned int* __restrict__ counter,
          float* __restrict__ out) {
    __shared__ float4 tile[2048];
    __shared__ float mred[256];
    __shared__ double dred[5][4];
    __shared__ float isLast;
    const int tid = threadIdx.x;
    const int chunk = blockIdx.x, b = blockIdx.y, dir = blockIdx.z;
    const float* src = samples + ((size_t)dir*B + b)*NS*3;
    const float* dst = samples + ((size_t)(1-dir)*B + b)*NS*3;
    for (int k = tid; k < 2048; k += 256) {
        const float* p = dst + (size_t)k*3;
        tile[k] = make_float4(p[0], p[1], p[2], 0.f);
    }
    int s = tid & 31, oct = tid >> 5;
    const float* sp = src + (size_t)(chunk*32 + s)*3;
    float px = sp[0], py = sp[1], pz = sp[2];
    __syncthreads();
    float mn = 3.402823466e38f;
    int j0 = oct*256;
    #pragma unroll 4
    for (int j = j0; j < j0 + 256; ++j) {
        float4 t = tile[j];
        float dx = px-t.x, dy = py-t.y, dz = pz-t.z;
        mn = fminf(mn, fmaf(dx, dx, fmaf(dy, dy, dz*dz)));
    }
    mred[tid] = mn;
    __syncthreads();
    if (tid < 32) {
        float m = mred[tid];
        #pragma unroll
        for (int o = 1; o < 8; ++o) m = fminf(m, mred[tid + o*32]);
        mred[tid] = m;
    }
    __syncthreads();
    if (tid == 0) {
        float sm = 0.f;
        #pragma unroll
        for (int i = 0; i < 32; ++i) sm += mred[i];
        chamPart[((size_t)dir*B + b)*64 + chunk] = sm;
        __threadfence();
        unsigned int old = atomicAdd(counter, 1u);
        unsigned int total = gridDim.x * gridDim.y * gridDim.z;
        isLast = (old == total - 1u) ? 1.f : 0.f;
    }
    __syncthreads();
    if (isLast == 0.f) return;
    __threadfence();

    int nCh = B*64;
    double a0 = 0, a1 = 0, aE = 0, aP = 0, aL = 0;
    for (int k = tid; k < nCh; k += 256) a0 += (double)chamPart[k];
    for (int k = nCh + tid; k < 2*nCh; k += 256) a1 += (double)chamPart[k];
    for (int k = tid; k < nbE; k += 256) aE += (double)partE[k];
    for (int k = tid; k < nbP; k += 256) aP += (double)partP[k];
    for (int k = tid; k < nbL; k += 256) aL += (double)partL[k];
    double v5[5] = {a0, a1, aE, aP, aL};
    int lane = tid & 63, w = tid >> 6;
    #pragma unroll
    for (int r = 0; r < 5; ++r) {
        double x = v5[r];
        #pragma unroll
        for (int o = 32; o > 0; o >>= 1) x += __shfl_down(x, o, 64);
        if (lane == 0) dred[r][w] = x;
    }
    __syncthreads();
    if (tid == 0) {
        double bn = (double)B * NS;
        double ch = (dred[0][0]+dred[0][1]+dred[0][2]+dred[0][3]) / bn
                  + (dred[1][0]+dred[1][1]+dred[1][2]+dred[1][3]) / bn;
        double ed = (dred[2][0]+dred[2][1]+dred[2][2]+dred[2][3]) / ((double)B*E);
        double no = (dred[3][0]+dred[3][1]+dred[3][2]+dred[3][3]) / ((double)B*P);
        double la = (dred[4][0]+dred[4][1]+dred[4][2]+dred[4][3]) / ((double)B*NV);
        double loss = ch + ed + 0.1*no + 0.1*la;
        out[0] = (float)loss; out[1] = (float)ch; out[2] = (float)ed;
        out[3] = (float)no;   out[4] = (float)la;
    }
}

extern "C" void kernel_launch(void* const* d_in, const int* in_sizes, int n_in,
                              void* d_out, int out_size, void* d_ws, size_t ws_size,
                              hipStream_t stream) {
    const float* vp = (const float*)d_in[0];
    const float* vt = (const float*)d_in[1];
    const int* edges = (const int*)d_in[3];
    const int* ncp   = (const int*)d_in[4];
    int B = in_sizes[0] / (3*NV);
    int E = in_sizes[3] / 2;
    int P = in_sizes[4] / 4;

    char* ws = (char*)d_ws;
    size_t off = 0;
    float* areas    = (float*)(ws + off); off += (size_t)2*B*NF*sizeof(float);   // 8.3 MB
    float* samples  = (float*)(ws + off); off += (size_t)2*B*NS*3*sizeof(float); // 393 KB
    float* blockmax = (float*)(ws + off); off += 8192*sizeof(float);
    float* chamPart = (float*)(ws + off); off += 2048*sizeof(float);
    float* partE    = (float*)(ws + off); off += 4096*sizeof(float);
    float* partP    = (float*)(ws + off); off += 4096*sizeof(float);
    float* partL    = (float*)(ws + off); off += 1024*sizeof(float);
    unsigned int* counter = (unsigned int*)(ws + off); off += 64;

    int nbA = (2*B*CELLS + 255)/256;        // 4065
    int nbE = (B*E + 1023)/1024;            // ~1529
    int nbP = (B*P + 1023)/1024;            // ~1521
    int nbL = (B*NV)/1024;                  // 512 (exact)
    k_prep<<<nbA + nbE + nbP + nbL, 256, 0, stream>>>(
        vp, vt, edges, ncp, B, E, P, nbA, nbE, nbP,
        areas, blockmax, partE, partP, partL, counter);
    k_sample<<<(2*B*NS)/256, 256, 0, stream>>>(vp, vt, B, areas, blockmax, nbA, samples);
    dim3 gch(64, B, 2);
    k_chamfer<<<gch, 256, 0, stream>>>(samples, B, partE, partP, partL,
                                       nbE, nbP, nbL, E, P,
                                       chamPart, counter, (float*)d_out);
}